// Round 2
// baseline (538.702 us; speedup 1.0000x reference)
//
#include <hip/hip_runtime.h>

// BSplineBasis: T=262144 samples, K=512 cubic (DEGREE=3) basis functions,
// clamped knot vector of 516 fp32 knots. Only 4 bases are nonzero per sample
// (window [j0, j0+3]); output is dense (T, 512) fp32 = 512 MiB.
// Strategy: pure-zero wide stores for the whole tile (store-BW-bound,
// ~2 instr/float4), then threads 0..15 overwrite their row's 4-float window
// from registers. R1 showed the select-per-element version was VALU-bound at
// ~2x the store-ceiling time.

namespace {
constexpr int K_N  = 512;    // output columns
constexpr int NKN  = 516;    // K + DEGREE + 1 knots
constexpr int DEG  = 3;
constexpr float EPSF = 1e-6f;
constexpr int ROWS = 16;     // rows (t samples) per block
constexpr int BLK  = 256;    // threads per block (4 waves)
}

__global__ __launch_bounds__(BLK)
void bspline_basis_kernel(const float* __restrict__ t_arr,
                          const float* __restrict__ knots,
                          float* __restrict__ out)
{
    __shared__ float kv[NKN];

    const int tid = threadIdx.x;
    for (int i = tid; i < NKN; i += BLK) kv[i] = knots[i];

    const int row_base = blockIdx.x * ROWS;
    float4* out4 = reinterpret_cast<float4*>(out + (size_t)row_base * K_N);

    __syncthreads();   // kv staged

    // ---- Phase 1 (wave 0, threads 0..15): window index + 4 basis values ----
    int   j0 = -1;
    float N0 = 0.f, N1 = 0.f, N2 = 0.f, N3 = 0.f;
    if (tid < ROWS) {
        const float t = t_arr[row_base + tid];
        // Reference semantics: the closed last degree-0 interval (j=514) dies
        // at d=1 since kv[515]-kv[514]=0 < EPS, so t >= kv[512] => zero row.
        if (t < kv[K_N]) {
            // Largest s in [3, 511] with kv[s] <= t (kv[s] <= t < kv[s+1]),
            // same fp32 comparisons as the reference's degree-0 test.
            int lo = DEG, hi = K_N - 1;
            while (lo < hi) {
                const int mid = (lo + hi + 1) >> 1;
                if (t >= kv[mid]) lo = mid; else hi = mid - 1;
            }
            const int s = lo;
            float N[4] = {1.f, 0.f, 0.f, 0.f};
            #pragma unroll
            for (int d = 1; d <= DEG; ++d) {
                float nn[4];
                #pragma unroll
                for (int k = 0; k <= d; ++k) {
                    const int j = s - d + k;
                    const float left  = (k >= 1)     ? N[k - 1] : 0.f;
                    const float right = (k <= d - 1) ? N[k]     : 0.f;
                    const float den1 = kv[j + d]     - kv[j];
                    const float den2 = kv[j + d + 1] - kv[j + 1];
                    const float c1 = (den1 >= EPSF) ? (t - kv[j]) / den1 : 0.f;
                    const float c2 = (den2 >= EPSF) ? (kv[j + d + 1] - t) / den2 : 0.f;
                    nn[k] = c1 * left + c2 * right;
                }
                #pragma unroll
                for (int k = 0; k <= d; ++k) N[k] = nn[k];
            }
            j0 = s - DEG;                 // in [0, 508]
            N0 = N[0]; N1 = N[1]; N2 = N[2]; N3 = N[3];
        }
    }

    // ---- Phase 2: zero-fill the whole 16x512 tile with wide stores ----
    const float4 z = make_float4(0.f, 0.f, 0.f, 0.f);
    constexpr int TOTAL_F4 = ROWS * (K_N / 4);      // 2048 float4 / block
    #pragma unroll
    for (int it = 0; it < TOTAL_F4 / BLK; ++it)     // 8 stores / thread
        out4[it * BLK + tid] = z;                   // consecutive lanes -> consecutive 16B

    __syncthreads();   // block-scope fence: zeros visible before window write

    // ---- Phase 3: overwrite the 4-wide nonzero window (registers -> global) ----
    if (tid < ROWS && j0 >= 0) {
        float* p = out + (size_t)(row_base + tid) * K_N + j0;
        p[0] = N0; p[1] = N1; p[2] = N2; p[3] = N3;
    }
}

extern "C" void kernel_launch(void* const* d_in, const int* in_sizes, int n_in,
                              void* d_out, int out_size, void* d_ws, size_t ws_size,
                              hipStream_t stream) {
    const float* t_arr = (const float*)d_in[0];
    const float* knots = (const float*)d_in[1];
    float* out = (float*)d_out;
    const int n_rows = in_sizes[0];                 // 262144, divisible by ROWS
    dim3 grid(n_rows / ROWS);
    hipLaunchKernelGGL(bspline_basis_kernel, grid, dim3(BLK), 0, stream,
                       t_arr, knots, out);
}